// Round 6
// baseline (278.426 us; speedup 1.0000x reference)
//
#include <hip/hip_runtime.h>
#include <stdint.h>
#include <math.h>

typedef unsigned long long u64;
typedef unsigned int u32;

#define NPI   360000
#define B_IMG 8
#define PRE   1000
#define POST  300
#define CAP   4096
#define NMSF  0.7f
#define IMG_W 800.0f
#define IMG_H 800.0f

#define NBIN    4096          // 12-bit sortable-key histogram (fallback path)
#define KSHIFT  20            // fkey >> 20 -> 12-bit bin
#define NGRP    64            // coarse groups (fallback select)
#define CHUNK_C 48            // compact blocks per image
#define F4PB_C  (NPI / 4 / CHUNK_C)   // 1875
#define EPB_C   (NPI / CHUNK_C)       // 7500
#define PBLK    128           // per-compact-block candidate region (16-sigma headroom)
#define RANKB   7             // rank continuation blocks per image (last 7 tickets)

// Fixed conservative threshold: logit >= 2.62 -> E[count] ~ 1584 per image
// (>=PRE by 14 sigma, <=CAP by 60 sigma). Rank phase VALIDATES the counts and
// falls back to an exact histogram-select recompute if ever violated.
#define THR_LOGIT 2.62f

// ---- workspace layout (bytes) ----
#define C1_OFF      0                 // 8*4: compact ticket counters
#define C2_OFF      64                // 8*4: iou ticket counters
#define VALID_OFF   256               // 8*16*8 = 1024          -> 1280
#define ZERO_BYTES  1280              // c1 + c2 + validw (one tiny memset)
#define BCNT_OFF    4096              // 8*48*4 = 1536
#define PCAND_OFF   8192              // 8*48*128*8 = 393216    -> 401408
#define BOX_OFF     401408            // 8*1000*16   = 128000   -> 529408
#define SCORE_OFF   529408            // 8*1000*4    = 32000    -> 561408
#define MASK_OFF    561408            // 8*1000*16*8 = 1024000  -> 1585408

#define LDSROWS 496

__device__ __forceinline__ u32 fkey(float f) {
  u32 u = __float_as_uint(f);
  return (u & 0x80000000u) ? ~u : (u | 0x80000000u);  // ascending-order bits
}
__device__ __forceinline__ u64 rl64(u64 v, int lane) {
  u32 lo = (u32)__builtin_amdgcn_readlane((int)(u32)v, lane);
  u32 hi = (u32)__builtin_amdgcn_readlane((int)(u32)(v >> 32), lane);
  return ((u64)hi << 32) | lo;
}
__device__ __forceinline__ u64 sx64(u64 v, int m) {
  u32 lo = (u32)__shfl_xor((int)(u32)v, m, 64);
  u32 hi = (u32)__shfl_xor((int)(u32)(v >> 32), m, 64);
  return ((u64)hi << 32) | lo;
}

// ---- emit one ranked candidate (numerics identical to ref) ----
__device__ __forceinline__ void emit_row(
    int img, int row, u64 key,
    const float* __restrict__ deltas, const float* __restrict__ anchors,
    float4* __restrict__ boxes, float* __restrict__ scores, u64* __restrict__ validw) {
  u32 hi  = (u32)(key >> 32);
  u32 idx = 0xFFFFFFFFu - (u32)(key & 0xFFFFFFFFu);
  u32 su  = (hi & 0x80000000u) ? (hi ^ 0x80000000u) : ~hi;
  float sc = __uint_as_float(su);
  size_t off = (size_t)img * NPI + idx;
  float4 d = ((const float4*)deltas)[off];
  float4 a = ((const float4*)anchors)[off];
  float aw = a.z - a.x, ah = a.w - a.y;
  float acx = a.x + 0.5f * aw, acy = a.y + 0.5f * ah;
  float cx = d.x * aw + acx, cy = d.y * ah + acy;
  float w = expf(d.z) * aw, h = expf(d.w) * ah;
  float x1 = cx - 0.5f * w, y1 = cy - 0.5f * h;
  float x2 = cx + 0.5f * w, y2 = cy + 0.5f * h;
  x1 = fminf(fmaxf(x1, 0.f), IMG_W);
  y1 = fminf(fmaxf(y1, 0.f), IMG_H);
  x2 = fminf(fmaxf(x2, 0.f), IMG_W);
  y2 = fminf(fmaxf(y2, 0.f), IMG_H);
  boxes[img * PRE + row]  = make_float4(x1, y1, x2, y2);
  scores[img * PRE + row] = sc;
  if (((x2 - x1) >= 1e-3f) && ((y2 - y1) >= 1e-3f))
    atomicOr(&validw[img * 16 + (row >> 6)], 1ull << (row & 63));
}

// ================== K1: compact + ticket-joined rank ==================
// 48 blocks/image compact; each rings a device-scope ticket. The last 7
// ticket holders spin (peers guaranteed resident: 384 small blocks) until
// all 48 are done, then run the proven 7-slice windowed rank in-place.
__global__ __launch_bounds__(256) void k_compact_rank(
    const float* __restrict__ logits,
    const float* __restrict__ deltas, const float* __restrict__ anchors,
    u32* __restrict__ bcnt_blk, u64* __restrict__ pcand,
    float4* __restrict__ boxes, float* __restrict__ scores,
    u64* __restrict__ validw, u32* __restrict__ c1) {
  __shared__ u64 skey[CAP];           // 32 KB (fallback aliases first 16 KB as hist)
  __shared__ u32 pc[4][256];          // per-wave partial counts
  __shared__ u32 scnt[CHUNK_C], soff[CHUNK_C];
  __shared__ int sn, sbad, stb, sticket;
  __shared__ u32 rc, bcnt;
  const int img = blockIdx.y, c = blockIdx.x;
  const int tid = threadIdx.x;
  const u32 FK0 = fkey(THR_LOGIT);
  if (tid == 0) bcnt = 0;
  __syncthreads();
  // ---- compact phase ----
  {
    const float4* L = (const float4*)(logits + (size_t)img * NPI) + (size_t)c * F4PB_C;
    u64* P = pcand + ((size_t)img * CHUNK_C + c) * PBLK;
    const int ebase = c * EPB_C;
#pragma unroll
    for (int k = 0; k < 8; k++) {
      int i = tid + k * 256;
      if (i < F4PB_C) {
        float4 v = L[i];
        float xs[4] = {v.x, v.y, v.z, v.w};
#pragma unroll
        for (int q = 0; q < 4; q++) {
          float x = xs[q];
          if (fkey(x) >= FK0) {
            // fp32 sigmoid with correctly-rounded exp: replicates numpy f32
            // tie structure exactly (verified: absmax 0.0)
            float ef = (float)exp(-(double)x);
            float sg = 1.0f / (1.0f + ef);
            u32 e = (u32)(ebase + 4 * i + q);
            u32 p = atomicAdd(&bcnt, 1u);
            if (p < PBLK)
              P[p] = ((u64)fkey(sg) << 32) | (u64)(0xFFFFFFFFu - e);
          }
        }
      }
    }
    __syncthreads();
    if (tid == 0) bcnt_blk[img * CHUNK_C + c] = bcnt;   // uncapped (overflow detect)
  }
  // ---- ticket (release) ----
  __threadfence();
  if (tid == 0) sticket = (int)atomicAdd(&c1[img], 1u);
  __syncthreads();
  const int rk = sticket - (CHUNK_C - RANKB);   // >=0 for last 7 finishers
  if (rk < 0) return;
  if (tid == 0) {
    while (__hip_atomic_load(&c1[img], __ATOMIC_ACQUIRE, __HIP_MEMORY_SCOPE_AGENT)
           < (u32)CHUNK_C)
      __builtin_amdgcn_s_sleep(8);
  }
  __syncthreads();
  __threadfence();                    // acquire: peers' pcand/bcnt now visible
  // ---- rank phase: validate, gather, windowed exact rank ----
  const int w = tid >> 6, l = tid & 63;
  if (tid < CHUNK_C) scnt[tid] = bcnt_blk[img * CHUNK_C + tid];
  if (tid == 0) { sbad = 0; stb = 0; rc = 0; }
  __syncthreads();
  if (tid < 64) {
    u32 m = (tid < CHUNK_C) ? (scnt[tid] > (u32)PBLK ? (u32)PBLK : scnt[tid]) : 0u;
    u64 bb = __ballot(tid < CHUNK_C && scnt[tid] > (u32)PBLK);   // region overflow?
    u32 x = m;
#pragma unroll
    for (int off = 1; off < 64; off <<= 1) {
      u32 o = (u32)__shfl_up((int)x, off, 64);
      if (l >= off) x += o;
    }
    if (tid < CHUNK_C) soff[tid] = x - m;     // exclusive prefix
    u32 tot = (u32)__builtin_amdgcn_readlane((int)x, 63);
    if (tid == 0) {
      sn = (int)tot;
      if (bb != 0ull || tot < (u32)PRE || tot > (u32)CAP) sbad = 1;
    }
  }
  __syncthreads();
  int n = sn;
  if (!sbad) {
    if (rk * 256 >= n) return;        // this slice has no rows
    // deterministic gather -> identical skey across the 7 rank blocks
    for (int cc = w; cc < CHUNK_C; cc += 4) {
      u32 mc = scnt[cc];
      u32 off = soff[cc];
      const u64* src = pcand + ((size_t)img * CHUNK_C + cc) * PBLK;
      for (u32 j = l; j < mc; j += 64) skey[off + j] = src[j];
    }
    __syncthreads();
    // windows rk, rk+7, ... cover all n slots
    for (int win = rk; win * 256 < n; win += RANKB) {
      const int base = win * 256;
      const int r0 = base + l, r1 = r0 + 64, r2 = r0 + 128, r3 = r0 + 192;
      u64 k0 = (r0 < n) ? skey[r0] : 0ull;
      u64 k1 = (r1 < n) ? skey[r1] : 0ull;
      u64 k2 = (r2 < n) ? skey[r2] : 0ull;
      u64 k3 = (r3 < n) ? skey[r3] : 0ull;
      int c0 = 0, c1v = 0, c2v = 0, c3v = 0;
      const int js = (w * n) >> 2, je = ((w + 1) * n) >> 2;   // disjoint cover
      int j = js;
      for (; j + 8 <= je; j += 8) {   // 8-wide: LDS reads pipeline, no chain
        u64 b0 = skey[j + 0], b1 = skey[j + 1], b2 = skey[j + 2], b3 = skey[j + 3];
        u64 b4 = skey[j + 4], b5 = skey[j + 5], b6 = skey[j + 6], b7 = skey[j + 7];
        c0  += (b0 > k0) + (b1 > k0) + (b2 > k0) + (b3 > k0)
             + (b4 > k0) + (b5 > k0) + (b6 > k0) + (b7 > k0);
        c1v += (b0 > k1) + (b1 > k1) + (b2 > k1) + (b3 > k1)
             + (b4 > k1) + (b5 > k1) + (b6 > k1) + (b7 > k1);
        c2v += (b0 > k2) + (b1 > k2) + (b2 > k2) + (b3 > k2)
             + (b4 > k2) + (b5 > k2) + (b6 > k2) + (b7 > k2);
        c3v += (b0 > k3) + (b1 > k3) + (b2 > k3) + (b3 > k3)
             + (b4 > k3) + (b5 > k3) + (b6 > k3) + (b7 > k3);
      }
      for (; j < je; j++) {
        u64 kj = skey[j];
        c0 += (kj > k0); c1v += (kj > k1); c2v += (kj > k2); c3v += (kj > k3);
      }
      pc[w][l]       = (u32)c0;
      pc[w][l + 64]  = (u32)c1v;
      pc[w][l + 128] = (u32)c2v;
      pc[w][l + 192] = (u32)c3v;
      __syncthreads();
      const int rr = base + tid;
      if (rr < n) {
        int cr = (int)(pc[0][tid] + pc[1][tid] + pc[2][tid] + pc[3][tid]);
        if (cr < PRE) emit_row(img, cr, skey[rr], deltas, anchors, boxes, scores, validw);
      }
      __syncthreads();                // pc reuse across windows
    }
  } else {
    // ===== exact fallback: rebuild hist, exact threshold bin, recompact =====
    // (never taken for the benchmark distribution; bit-exact if taken)
    u32* hh = (u32*)skey;             // alias first 16 KB
    for (int i = tid; i < NBIN; i += 256) hh[i] = 0;
    __syncthreads();
    const float4* L = (const float4*)(logits + (size_t)img * NPI);
    for (int i = tid; i < NPI / 4; i += 256) {
      float4 v = L[i];
      atomicAdd(&hh[fkey(v.x) >> KSHIFT], 1u);
      atomicAdd(&hh[fkey(v.y) >> KSHIFT], 1u);
      atomicAdd(&hh[fkey(v.z) >> KSHIFT], 1u);
      atomicAdd(&hh[fkey(v.w) >> KSHIFT], 1u);
    }
    __syncthreads();
    if (tid < 64) {
      u32 cg = 0;
      for (int b = 0; b < NBIN / NGRP; b++) cg += hh[tid * (NBIN / NGRP) + b];
      u32 suf = cg;
#pragma unroll
      for (int off = 1; off < 64; off <<= 1) {
        u32 o = (u32)__shfl_down((int)suf, off, 64);
        if (tid + off < 64) suf += o;
      }
      u32 sx = suf - cg;
      u64 bal = __ballot(suf >= (u32)PRE && sx < (u32)PRE);
      if (bal) {
        int gc = __builtin_ctzll(bal);
        u32 s_above = (u32)__shfl((int)sx, gc, 64);
        u32 fb = hh[gc * (NBIN / NGRP) + tid];
        u32 fsuf = fb;
#pragma unroll
        for (int off = 1; off < 64; off <<= 1) {
          u32 o = (u32)__shfl_down((int)fsuf, off, 64);
          if (tid + off < 64) fsuf += o;
        }
        u32 fincl = fsuf + s_above, fexcl = fincl - fb;
        if (fincl >= (u32)PRE && fexcl < (u32)PRE) stb = gc * (NBIN / NGRP) + tid;
      }
    }
    __syncthreads();
    const int tb = stb;
    for (int i = tid; i < NPI / 4; i += 256) {
      float4 v = L[i];
      float xs[4] = {v.x, v.y, v.z, v.w};
#pragma unroll
      for (int q = 0; q < 4; q++) {
        float x = xs[q];
        if ((int)(fkey(x) >> KSHIFT) >= tb) {
          float ef = (float)exp(-(double)x);
          float sg = 1.0f / (1.0f + ef);
          u32 e = (u32)(4 * i + q);
          u32 p = atomicAdd(&rc, 1u);
          if (p < CAP) skey[p] = ((u64)fkey(sg) << 32) | (u64)(0xFFFFFFFFu - e);
        }
      }
    }
    __syncthreads();
    n = (int)(rc < (u32)CAP ? rc : (u32)CAP);
    // per-block skey ORDER nondeterministic -> each of the 7 blocks ranks ALL
    // entries (identical idempotent writes; correct, slow, never hit)
    for (int r = tid; r < n; r += 256) {
      u64 kr = skey[r];
      int cr = 0;
      for (int j = 0; j < n; j++) cr += (skey[j] > kr);
      if (cr < PRE) emit_row(img, cr, kr, deltas, anchors, boxes, scores, validw);
    }
  }
}

// ================== K2: iou + ticket-joined nms ==================
// 32 blocks/image compute the suppression mask (32 rows x 16 words each);
// the LAST finisher per image runs the greedy NMS scan in-place (no spin).
__global__ __launch_bounds__(512) void k_iou_nms(
    const float4* __restrict__ boxes, const float* __restrict__ scores,
    const u64* __restrict__ validw, u64* __restrict__ mask,
    float* __restrict__ out, u32* __restrict__ c2) {
  __shared__ union {
    struct { float4 sb[1024]; float sa[1024]; } iou;                    // 20 KB
    struct { u64 smask[LDSROWS * 16]; int keeplist[POST]; int kept; } nms; // 64.7 KB
  } lds;
  __shared__ int slast;
  const int img = blockIdx.y, rb = blockIdx.x;   // rb: 32-row block 0..31
  const int tid = threadIdx.x;
  // ---- iou phase ----
  for (int j = tid; j < 1024; j += 512) {
    float4 b = (j < PRE) ? boxes[img * PRE + j] : make_float4(0.f, 0.f, 0.f, 0.f);
    lds.iou.sb[j] = b;
    lds.iou.sa[j] = (b.z - b.x) * (b.w - b.y);
  }
  __syncthreads();
  {
    const int i  = rb * 32 + (tid & 31);   // row 0..1023
    const int wv = tid >> 5;               // word 0..15
    const bool rowok = (i < PRE);
    const int cbase = wv << 6;
    u64 bits = 0;
    if (cbase + 63 >= rb * 32) {           // live word (not fully masked upper-tri)
      const float4 bi = lds.iou.sb[i];
      const float  ai = lds.iou.sa[i];
#pragma unroll
      for (int k = 0; k < 64; k++) {
        int cc = cbase + k;
        float4 bc = lds.iou.sb[cc];        // half-wave-uniform broadcast read
        float ac  = lds.iou.sa[cc];
        float ltx = fmaxf(bi.x, bc.x), lty = fmaxf(bi.y, bc.y);
        float rbx = fminf(bi.z, bc.z), rby = fminf(bi.w, bc.w);
        float iw = fmaxf(rbx - ltx, 0.f), ih = fmaxf(rby - lty, 0.f);
        float inter = iw * ih;
        float iou = inter / (ai + ac - inter + 1e-9f);  // IEEE div, matches ref
        bits |= (iou > NMSF) ? (1ull << k) : 0ull;
      }
      int d = i - cbase;
      u64 gtmask = (d < 0) ? ~0ull : ((d >= 63) ? 0ull : (~0ull << (d + 1)));
      int rem = PRE - cbase;
      u64 tmask = (rem >= 64) ? ~0ull : ((rem <= 0) ? 0ull : ((1ull << rem) - 1ull));
      bits &= gtmask & tmask;
    }
    if (rowok) mask[((size_t)img * PRE + i) * 16 + wv] = bits;
  }
  // ---- ticket (release); last finisher continues into NMS ----
  __threadfence();
  if (tid == 0) slast = ((int)atomicAdd(&c2[img], 1u) == 31);
  __syncthreads();                     // also: all iou LDS reads done before reuse
  if (!slast) return;
  __threadfence();                     // acquire: peers' mask words visible
  // ---- nms phase (512 threads) ----
  const u64* M = mask + (size_t)img * PRE * 16;
  u64 diag[16];
  if (tid < 64) {
#pragma unroll
    for (int cc = 0; cc < 16; cc++) {
      int row = cc * 64 + tid;
      diag[cc] = (row < PRE) ? M[(size_t)row * 16 + cc] : 0ull;
    }
  }
  for (int e = tid; e < LDSROWS * 16; e += 512) lds.nms.smask[e] = M[e];
  __syncthreads();
  if (tid < 64) {
    const int lane = tid;
    const int w = lane & 15, g = lane >> 4;
    u64 rem = ~0ull;
    if (lane < 16) {
      rem = ~validw[img * 16 + lane];
      if (lane == 15) rem |= 0xFFFFFF0000000000ull;  // rows 1000..1023 invalid
    }
    int kept = 0;
#pragma unroll
    for (int cc = 0; cc < 16; cc++) {
      u64 alive = ~rl64(rem, cc);      // wave-uniform
      int kept0 = kept;
      while (alive != 0ull && kept < POST) {
        int r = __builtin_ctzll(alive);
        if (lane == 0) lds.nms.keeplist[kept] = cc * 64 + r;
        kept++;
        u64 sup = rl64(diag[cc], r);   // row's in-chunk suppression word
        alive &= ~sup;
        alive &= ~(1ull << r);
      }
      int nc = kept - kept0;
      if (nc > 0 && kept < POST && cc < 15) {
        u64 part = 0;
        for (int j = g; j < nc; j += 4) {
          int row = lds.nms.keeplist[kept0 + j];
          part |= (row < LDSROWS) ? lds.nms.smask[row * 16 + w]
                                  : M[(size_t)row * 16 + w];
        }
        part |= sx64(part, 16);
        part |= sx64(part, 32);
        rem |= part;                   // only lanes <16 meaningful
      }
      if (kept >= POST) break;
    }
    if (lane == 0) lds.nms.kept = kept;
  }
  __syncthreads();
  for (int o = tid; o < POST; o += 512) {
    float4 bx = make_float4(0.f, 0.f, 0.f, 0.f);
    float  sc = 0.f;
    if (o < lds.nms.kept) {
      int i2 = lds.nms.keeplist[o];
      bx = boxes[img * PRE + i2];
      sc = scores[img * PRE + i2];
    }
    float* op = out + ((size_t)img * POST + o) * 5;
    op[0] = bx.x; op[1] = bx.y; op[2] = bx.z; op[3] = bx.w; op[4] = sc;
  }
}

extern "C" void kernel_launch(void* const* d_in, const int* in_sizes, int n_in,
                              void* d_out, int out_size, void* d_ws, size_t ws_size,
                              hipStream_t stream) {
  const float* logits  = (const float*)d_in[0];
  const float* deltas  = (const float*)d_in[1];
  const float* anchors = (const float*)d_in[2];
  float* out = (float*)d_out;
  char* ws = (char*)d_ws;

  u32* c1       = (u32*)(ws + C1_OFF);
  u32* c2       = (u32*)(ws + C2_OFF);
  u64* validw   = (u64*)(ws + VALID_OFF);
  u32* bcnt_blk = (u32*)(ws + BCNT_OFF);
  u64* pcand    = (u64*)(ws + PCAND_OFF);
  float4* boxes = (float4*)(ws + BOX_OFF);
  float* scores = (float*)(ws + SCORE_OFF);
  u64* mask     = (u64*)(ws + MASK_OFF);

  hipMemsetAsync(ws, 0, ZERO_BYTES, stream);   // c1 + c2 + validw (1.3 KB)
  dim3 gc(CHUNK_C, B_IMG);
  k_compact_rank<<<gc, 256, 0, stream>>>(logits, deltas, anchors, bcnt_blk, pcand,
                                         boxes, scores, validw, c1);
  dim3 g2(32, B_IMG);
  k_iou_nms<<<g2, 512, 0, stream>>>(boxes, scores, validw, mask, out, c2);
}

// Round 7
// 181.897 us; speedup vs baseline: 1.5307x; 1.5307x over previous
//
#include <hip/hip_runtime.h>
#include <stdint.h>
#include <math.h>

typedef unsigned long long u64;
typedef unsigned int u32;

#define NPI   360000
#define B_IMG 8
#define PRE   1000
#define POST  300
#define CAP   4096
#define NMSF  0.7f
#define IMG_W 800.0f
#define IMG_H 800.0f

#define NBIN    4096          // 12-bit sortable-key histogram (fallback path)
#define KSHIFT  20            // fkey >> 20 -> 12-bit bin
#define NGRP    64            // coarse groups (fallback select)
#define CHUNK_C 48            // compact blocks per image
#define F4PB_C  (NPI / 4 / CHUNK_C)   // 1875
#define EPB_C   (NPI / CHUNK_C)       // 7500
#define PBLK    128           // per-compact-block candidate region (16-sigma headroom)

// Fixed conservative threshold: logit >= 2.62 -> E[count] ~ 1584 per image
// (>=PRE by 14 sigma, <=CAP by 60 sigma). k_rank VALIDATES the counts and
// falls back to an exact histogram-select recompute if ever violated.
#define THR_LOGIT 2.62f

// ---- workspace layout (bytes) ----
#define VALID_OFF   256               // 8*16*8 = 1024          -> 1280
#define BCNT_OFF    4096              // 8*48*4 = 1536          -> 5632
#define PCAND_OFF   8192              // 8*48*128*8 = 393216    -> 401408
#define BOX_OFF     401408            // 8*1000*16   = 128000   -> 529408
#define SCORE_OFF   529408            // 8*1000*4    = 32000    -> 561408
#define MASK_OFF    561408            // 8*1000*16*8 = 1024000  -> 1585408

#define LDSROWS 496
#define NMS_T   320
#define RBLK    16            // rank blocks per image (256 candidate slots each)

__device__ __forceinline__ u32 fkey(float f) {
  u32 u = __float_as_uint(f);
  return (u & 0x80000000u) ? ~u : (u | 0x80000000u);  // ascending-order bits
}
__device__ __forceinline__ u64 rl64(u64 v, int lane) {
  u32 lo = (u32)__builtin_amdgcn_readlane((int)(u32)v, lane);
  u32 hi = (u32)__builtin_amdgcn_readlane((int)(u32)(v >> 32), lane);
  return ((u64)hi << 32) | lo;
}
__device__ __forceinline__ u64 sx64(u64 v, int m) {
  u32 lo = (u32)__shfl_xor((int)(u32)v, m, 64);
  u32 hi = (u32)__shfl_xor((int)(u32)(v >> 32), m, 64);
  return ((u64)hi << 32) | lo;
}

// ---- K1: compact candidates with fkey >= FK0 into per-block regions.
//      No histogram pass, no global atomics, no pre-zeroed counters. ----
__global__ __launch_bounds__(256) void k_compact(const float* __restrict__ logits,
                                                 u32* __restrict__ bcnt_blk,
                                                 u64* __restrict__ pcand,
                                                 u64* __restrict__ validw) {
  __shared__ u32 bcnt;
  const int img = blockIdx.y, c = blockIdx.x;
  const int t = threadIdx.x;
  const u32 FK0 = fkey(THR_LOGIT);
  if (t == 0) bcnt = 0;
  if (c == 0 && t < 16) validw[img * 16 + t] = 0;   // consumed by k_rank (next dispatch)
  __syncthreads();
  const float4* L = (const float4*)(logits + (size_t)img * NPI) + (size_t)c * F4PB_C;
  u64* P = pcand + ((size_t)img * CHUNK_C + c) * PBLK;
  const int ebase = c * EPB_C;
#pragma unroll
  for (int k = 0; k < 8; k++) {
    int i = t + k * 256;
    if (i < F4PB_C) {
      float4 v = L[i];
      float xs[4] = {v.x, v.y, v.z, v.w};
#pragma unroll
      for (int q = 0; q < 4; q++) {
        float x = xs[q];
        if (fkey(x) >= FK0) {
          // fp32 sigmoid with correctly-rounded exp: replicates numpy f32
          // tie structure exactly (verified: absmax 0.0)
          float ef = (float)exp(-(double)x);
          float sg = 1.0f / (1.0f + ef);
          u32 e = (u32)(ebase + 4 * i + q);
          u32 p = atomicAdd(&bcnt, 1u);
          if (p < PBLK)
            P[p] = ((u64)fkey(sg) << 32) | (u64)(0xFFFFFFFFu - e);
        }
      }
    }
  }
  __syncthreads();
  if (t == 0) bcnt_blk[img * CHUNK_C + c] = bcnt;   // uncapped (overflow detection)
}

// ---- emit one ranked candidate (numerics identical to ref) ----
__device__ __forceinline__ void emit_row(
    int img, int row, u64 key,
    const float* __restrict__ deltas, const float* __restrict__ anchors,
    float4* __restrict__ boxes, float* __restrict__ scores, u64* __restrict__ validw) {
  u32 hi  = (u32)(key >> 32);
  u32 idx = 0xFFFFFFFFu - (u32)(key & 0xFFFFFFFFu);
  u32 su  = (hi & 0x80000000u) ? (hi ^ 0x80000000u) : ~hi;
  float sc = __uint_as_float(su);
  size_t off = (size_t)img * NPI + idx;
  float4 d = ((const float4*)deltas)[off];
  float4 a = ((const float4*)anchors)[off];
  float aw = a.z - a.x, ah = a.w - a.y;
  float acx = a.x + 0.5f * aw, acy = a.y + 0.5f * ah;
  float cx = d.x * aw + acx, cy = d.y * ah + acy;
  float w = expf(d.z) * aw, h = expf(d.w) * ah;
  float x1 = cx - 0.5f * w, y1 = cy - 0.5f * h;
  float x2 = cx + 0.5f * w, y2 = cy + 0.5f * h;
  x1 = fminf(fmaxf(x1, 0.f), IMG_W);
  y1 = fminf(fmaxf(y1, 0.f), IMG_H);
  x2 = fminf(fmaxf(x2, 0.f), IMG_W);
  y2 = fminf(fmaxf(y2, 0.f), IMG_H);
  boxes[img * PRE + row]  = make_float4(x1, y1, x2, y2);
  scores[img * PRE + row] = sc;
  if (((x2 - x1) >= 1e-3f) && ((y2 - y1) >= 1e-3f))
    atomicOr(&validw[img * 16 + (row >> 6)], 1ull << (row & 63));
}

// ---- K2: validate counts, gather candidate regions -> LDS, exact rank +
//      decode/clip. Count loop 8-way load-batched (breaks the ds_read
//      latency chain: 8 independent LDS reads in flight per iteration). ----
__global__ __launch_bounds__(256) void k_rank(
    const float* __restrict__ logits,
    const float* __restrict__ deltas, const float* __restrict__ anchors,
    const u32* __restrict__ bcnt_blk, const u64* __restrict__ pcand,
    float4* __restrict__ boxes, float* __restrict__ scores, u64* __restrict__ validw) {
  __shared__ u64 skey[CAP];           // 32 KB (fallback aliases first 16 KB as hist)
  __shared__ u32 pc[4][256];          // per-wave partial counts
  __shared__ u32 scnt[CHUNK_C], soff[CHUNK_C];
  __shared__ int sn, sbad, stb;
  __shared__ u32 rc;
  const int img = blockIdx.y;
  const int tid = threadIdx.x;
  const int w = tid >> 6, l = tid & 63;
  if (tid < CHUNK_C) scnt[tid] = bcnt_blk[img * CHUNK_C + tid];
  if (tid == 0) { sbad = 0; stb = 0; rc = 0; }
  __syncthreads();
  if (tid < 64) {
    u32 m = (tid < CHUNK_C) ? (scnt[tid] > (u32)PBLK ? (u32)PBLK : scnt[tid]) : 0u;
    u64 bb = __ballot(tid < CHUNK_C && scnt[tid] > (u32)PBLK);   // region overflow?
    u32 x = m;
#pragma unroll
    for (int off = 1; off < 64; off <<= 1) {
      u32 o = (u32)__shfl_up((int)x, off, 64);
      if (l >= off) x += o;
    }
    if (tid < CHUNK_C) soff[tid] = x - m;     // exclusive prefix
    u32 tot = (u32)__builtin_amdgcn_readlane((int)x, 63);
    if (tid == 0) {
      sn = (int)tot;
      if (bb != 0ull || tot < (u32)PRE || tot > (u32)CAP) sbad = 1;
    }
  }
  __syncthreads();
  int n = sn;
  const int base = blockIdx.x * 256;
  if (!sbad) {
    if (base >= n) return;            // block-uniform early exit BEFORE gather
    // deterministic gather -> identical skey across all blocks of this image
    for (int c = w; c < CHUNK_C; c += 4) {
      u32 mc = scnt[c];
      u32 off = soff[c];
      const u64* src = pcand + ((size_t)img * CHUNK_C + c) * PBLK;
      for (u32 j = l; j < mc; j += 64) skey[off + j] = src[j];
    }
    __syncthreads();
  } else {
    // ===== exact fallback: rebuild hist, exact threshold bin, recompact =====
    // (never taken for the benchmark distribution; bit-exact if taken)
    u32* hh = (u32*)skey;             // alias first 16 KB
    for (int i = tid; i < NBIN; i += 256) hh[i] = 0;
    __syncthreads();
    const float4* L = (const float4*)(logits + (size_t)img * NPI);
    for (int i = tid; i < NPI / 4; i += 256) {
      float4 v = L[i];
      atomicAdd(&hh[fkey(v.x) >> KSHIFT], 1u);
      atomicAdd(&hh[fkey(v.y) >> KSHIFT], 1u);
      atomicAdd(&hh[fkey(v.z) >> KSHIFT], 1u);
      atomicAdd(&hh[fkey(v.w) >> KSHIFT], 1u);
    }
    __syncthreads();
    if (tid < 64) {
      u32 cg = 0;
      for (int b = 0; b < NBIN / NGRP; b++) cg += hh[tid * (NBIN / NGRP) + b];
      u32 suf = cg;
#pragma unroll
      for (int off = 1; off < 64; off <<= 1) {
        u32 o = (u32)__shfl_down((int)suf, off, 64);
        if (tid + off < 64) suf += o;
      }
      u32 sx = suf - cg;
      u64 bal = __ballot(suf >= (u32)PRE && sx < (u32)PRE);
      if (bal) {
        int gc = __builtin_ctzll(bal);
        u32 s_above = (u32)__shfl((int)sx, gc, 64);
        u32 fb = hh[gc * (NBIN / NGRP) + tid];
        u32 fsuf = fb;
#pragma unroll
        for (int off = 1; off < 64; off <<= 1) {
          u32 o = (u32)__shfl_down((int)fsuf, off, 64);
          if (tid + off < 64) fsuf += o;
        }
        u32 fincl = fsuf + s_above, fexcl = fincl - fb;
        if (fincl >= (u32)PRE && fexcl < (u32)PRE) stb = gc * (NBIN / NGRP) + tid;
      }
    }
    __syncthreads();
    const int tb = stb;
    for (int i = tid; i < NPI / 4; i += 256) {
      float4 v = L[i];
      float xs[4] = {v.x, v.y, v.z, v.w};
#pragma unroll
      for (int q = 0; q < 4; q++) {
        float x = xs[q];
        if ((int)(fkey(x) >> KSHIFT) >= tb) {
          float ef = (float)exp(-(double)x);
          float sg = 1.0f / (1.0f + ef);
          u32 e = (u32)(4 * i + q);
          u32 p = atomicAdd(&rc, 1u);
          if (p < CAP) skey[p] = ((u64)fkey(sg) << 32) | (u64)(0xFFFFFFFFu - e);
        }
      }
    }
    __syncthreads();
    n = (int)(rc < (u32)CAP ? rc : (u32)CAP);
    // per-block skey ORDER is nondeterministic here -> every block redundantly
    // ranks ALL entries (identical idempotent writes; correct, slow, never hit)
    for (int r = tid; r < n; r += 256) {
      u64 kr = skey[r];
      int cr = 0;
      for (int j = 0; j < n; j++) cr += (skey[j] > kr);
      if (cr < PRE) emit_row(img, cr, kr, deltas, anchors, boxes, scores, validw);
    }
    return;
  }
  // ---- fast path: windowed exact rank, sliced across 4 waves, loads
  //      batched 8-wide so the LDS reads pipeline instead of serializing ----
  const int r0 = base + l, r1 = r0 + 64, r2 = r0 + 128, r3 = r0 + 192;
  u64 k0 = (r0 < n) ? skey[r0] : 0ull;
  u64 k1 = (r1 < n) ? skey[r1] : 0ull;
  u64 k2 = (r2 < n) ? skey[r2] : 0ull;
  u64 k3 = (r3 < n) ? skey[r3] : 0ull;
  int c0 = 0, c1 = 0, c2 = 0, c3 = 0;
  const int js = (w * n) >> 2, je = ((w + 1) * n) >> 2;   // disjoint cover of [0,n)
  int j = js;
  for (; j + 8 <= je; j += 8) {
    u64 b0 = skey[j + 0], b1 = skey[j + 1], b2 = skey[j + 2], b3 = skey[j + 3];
    u64 b4 = skey[j + 4], b5 = skey[j + 5], b6 = skey[j + 6], b7 = skey[j + 7];
    c0 += (b0 > k0) + (b1 > k0) + (b2 > k0) + (b3 > k0)
        + (b4 > k0) + (b5 > k0) + (b6 > k0) + (b7 > k0);
    c1 += (b0 > k1) + (b1 > k1) + (b2 > k1) + (b3 > k1)
        + (b4 > k1) + (b5 > k1) + (b6 > k1) + (b7 > k1);
    c2 += (b0 > k2) + (b1 > k2) + (b2 > k2) + (b3 > k2)
        + (b4 > k2) + (b5 > k2) + (b6 > k2) + (b7 > k2);
    c3 += (b0 > k3) + (b1 > k3) + (b2 > k3) + (b3 > k3)
        + (b4 > k3) + (b5 > k3) + (b6 > k3) + (b7 > k3);
  }
  for (; j < je; j++) {
    u64 kj = skey[j];
    c0 += (kj > k0); c1 += (kj > k1); c2 += (kj > k2); c3 += (kj > k3);
  }
  pc[w][l]       = (u32)c0;
  pc[w][l + 64]  = (u32)c1;
  pc[w][l + 128] = (u32)c2;
  pc[w][l + 192] = (u32)c3;
  __syncthreads();
  const int rr = base + tid;
  if (rr < n) {
    int c = (int)(pc[0][tid] + pc[1][tid] + pc[2][tid] + pc[3][tid]);
    if (c < PRE) emit_row(img, c, skey[rr], deltas, anchors, boxes, scores, validw);
  }
}

// ---- K3: suppression bitmask. 256 blocks (1/CU, 2 waves/SIMD) x 512 thr;
//      32 rows x 16 words per block; dead (upper-triangle) words store 0. ----
__global__ __launch_bounds__(512) void k_iou(const float4* __restrict__ boxes,
                                             u64* __restrict__ mask) {
  __shared__ float4 sb[1024];
  __shared__ float  sa[1024];
  const int img = blockIdx.y, rb = blockIdx.x;   // rb: 32-row block 0..31
  const int tid = threadIdx.x;
  for (int j = tid; j < 1024; j += 512) {
    float4 b = (j < PRE) ? boxes[img * PRE + j] : make_float4(0.f, 0.f, 0.f, 0.f);
    sb[j] = b;
    sa[j] = (b.z - b.x) * (b.w - b.y);
  }
  __syncthreads();
  const int i  = rb * 32 + (tid & 31);   // row 0..1023
  const int wv = tid >> 5;               // word 0..15
  const bool rowok = (i < PRE);
  const int cbase = wv << 6;
  if (cbase + 63 < rb * 32) {            // whole word < every row in block -> masked out
    if (rowok) mask[((size_t)img * PRE + i) * 16 + wv] = 0ull;
    return;
  }
  const float4 bi = sb[i];
  const float  ai = sa[i];
  u64 bits = 0;
#pragma unroll
  for (int k = 0; k < 64; k++) {
    int c = cbase + k;
    float4 bc = sb[c];                   // half-wave-uniform broadcast read
    float ac  = sa[c];
    float ltx = fmaxf(bi.x, bc.x), lty = fmaxf(bi.y, bc.y);
    float rbx = fminf(bi.z, bc.z), rby = fminf(bi.w, bc.w);
    float iw = fmaxf(rbx - ltx, 0.f), ih = fmaxf(rby - lty, 0.f);
    float inter = iw * ih;
    float iou = inter / (ai + ac - inter + 1e-9f);  // IEEE div, matches ref
    bits |= (iou > NMSF) ? (1ull << k) : 0ull;
  }
  int d = i - cbase;
  u64 gtmask = (d < 0) ? ~0ull : ((d >= 63) ? 0ull : (~0ull << (d + 1)));
  int rem = PRE - cbase;
  u64 tmask = (rem >= 64) ? ~0ull : ((rem <= 0) ? 0ull : ((1ull << rem) - 1ull));
  bits &= gtmask & tmask;
  if (rowok) mask[((size_t)img * PRE + i) * 16 + wv] = bits;
}

// ---- K4: chunked greedy scan — scalar in-chunk decisions via readlane.
//      smask staged with uint4 (16B) loads: half the VMEM issue count. ----
__global__ __launch_bounds__(NMS_T) void k_nms(
    const u64* __restrict__ mask, const u64* __restrict__ validw,
    const float4* __restrict__ boxes, const float* __restrict__ scores,
    float* __restrict__ out) {
  __shared__ u64 smask[LDSROWS * 16];
  __shared__ int skeeplist[POST];
  __shared__ int skept;
  const int img = blockIdx.x;
  const int tid = threadIdx.x;
  const u64* M = mask + (size_t)img * PRE * 16;
  u64 diag[16];
  if (tid < 64) {
#pragma unroll
    for (int cc = 0; cc < 16; cc++) {
      int row = cc * 64 + tid;
      diag[cc] = (row < PRE) ? M[(size_t)row * 16 + cc] : 0ull;
    }
  }
  const uint4* M4 = (const uint4*)M;           // 16B-aligned (mask offset % 16 == 0)
  for (int e = tid; e < LDSROWS * 8; e += NMS_T) {
    uint4 v = M4[e];
    smask[2 * e]     = ((u64)v.y << 32) | (u64)v.x;
    smask[2 * e + 1] = ((u64)v.w << 32) | (u64)v.z;
  }
  __syncthreads();
  if (tid < 64) {
    const int lane = tid;
    const int w = lane & 15, g = lane >> 4;
    u64 rem = ~0ull;
    if (lane < 16) {
      rem = ~validw[img * 16 + lane];
      if (lane == 15) rem |= 0xFFFFFF0000000000ull;  // rows 1000..1023 invalid
    }
    int kept = 0;
#pragma unroll
    for (int cc = 0; cc < 16; cc++) {
      u64 alive = ~rl64(rem, cc);      // wave-uniform
      int kept0 = kept;
      while (alive != 0ull && kept < POST) {
        int r = __builtin_ctzll(alive);
        if (lane == 0) skeeplist[kept] = cc * 64 + r;
        kept++;
        u64 sup = rl64(diag[cc], r);   // row's in-chunk suppression word
        alive &= ~sup;
        alive &= ~(1ull << r);
      }
      int nc = kept - kept0;
      if (nc > 0 && kept < POST && cc < 15) {
        u64 part = 0;
        for (int j = g; j < nc; j += 4) {
          int row = skeeplist[kept0 + j];
          part |= (row < LDSROWS) ? smask[row * 16 + w] : M[(size_t)row * 16 + w];
        }
        part |= sx64(part, 16);
        part |= sx64(part, 32);
        rem |= part;                   // only lanes <16 meaningful
      }
      if (kept >= POST) break;
    }
    if (lane == 0) skept = kept;
  }
  __syncthreads();
  if (tid < POST) {
    float4 bx = make_float4(0.f, 0.f, 0.f, 0.f);
    float  sc = 0.f;
    if (tid < skept) {
      int i = skeeplist[tid];
      bx = boxes[img * PRE + i];
      sc = scores[img * PRE + i];
    }
    float* o = out + ((size_t)img * POST + tid) * 5;
    o[0] = bx.x; o[1] = bx.y; o[2] = bx.z; o[3] = bx.w; o[4] = sc;
  }
}

extern "C" void kernel_launch(void* const* d_in, const int* in_sizes, int n_in,
                              void* d_out, int out_size, void* d_ws, size_t ws_size,
                              hipStream_t stream) {
  const float* logits  = (const float*)d_in[0];
  const float* deltas  = (const float*)d_in[1];
  const float* anchors = (const float*)d_in[2];
  float* out = (float*)d_out;
  char* ws = (char*)d_ws;

  u64* validw   = (u64*)(ws + VALID_OFF);
  u32* bcnt_blk = (u32*)(ws + BCNT_OFF);
  u64* pcand    = (u64*)(ws + PCAND_OFF);
  float4* boxes = (float4*)(ws + BOX_OFF);
  float* scores = (float*)(ws + SCORE_OFF);
  u64* mask     = (u64*)(ws + MASK_OFF);

  dim3 gc(CHUNK_C, B_IMG);
  k_compact<<<gc, 256, 0, stream>>>(logits, bcnt_blk, pcand, validw);
  dim3 gr(RBLK, B_IMG);
  k_rank<<<gr, 256, 0, stream>>>(logits, deltas, anchors, bcnt_blk, pcand,
                                 boxes, scores, validw);
  dim3 g2(32, B_IMG);
  k_iou<<<g2, 512, 0, stream>>>(boxes, mask);
  k_nms<<<B_IMG, NMS_T, 0, stream>>>(mask, validw, boxes, scores, out);
}